// Round 13
// baseline (54.073 us; speedup 1.0000x reference)
//
#include <hip/hip_runtime.h>
#include <hip/hip_bf16.h>

// Shapes (fixed): B=4, M=1024, D=512. Device inputs f32 or bf16 (self-detected).
#define BB 4
#define MM 1024
#define DD 512
#define MT (BB*MM)          // 4096 total rows

typedef __bf16  bf16x8 __attribute__((ext_vector_type(8)));
typedef float   f32x4  __attribute__((ext_vector_type(4)));

typedef __attribute__((address_space(1))) const unsigned char gas_char;
typedef __attribute__((address_space(3))) unsigned char las_char;

__device__ __forceinline__ void gl_lds16(const void* g, void* l){
    // async global->LDS, 16B/lane; LDS dest = wave-uniform base + lane*16
    __builtin_amdgcn_global_load_lds((gas_char*)g, (las_char*)l, 16, 0, 0);
}

__device__ __forceinline__ float bf2f(ushort u){
    union{float f; unsigned u;} x; x.u = (unsigned)u << 16; return x.f;
}
__device__ __forceinline__ ushort f2bf(float f){
    union{float f; unsigned u;} x; x.f = f;
    unsigned r = x.u + 0x7FFF + ((x.u >> 16) & 1);   // RNE
    return (ushort)(r >> 16);
}

// Wave-uniform dtype detect: bf16 N(0,1) even half-words have sane exponents.
__device__ __forceinline__ int detect_bf16(const ushort* __restrict__ x){
    int lane = threadIdx.x & 63;
    ushort u = x[2*lane];
    int e = (u >> 7) & 0xFF;
    bool sane = (e >= 114 && e <= 140);
    unsigned long long b = __ballot(sane);
    return (__popcll(b) >= 48) ? 1 : 0;
}

// 8 consecutive elements at eidx (mult of 8) as packed bf16, converting if f32.
__device__ __forceinline__ uint4 ld8(const void* __restrict__ base, size_t eidx, int fl){
    if (fl) return ((const uint4*)base)[eidx >> 3];
    const float4* f = (const float4*)base + (eidx >> 2);
    float4 a = f[0], b = f[1];
    uint4 o;
    o.x = (uint)f2bf(a.x) | ((uint)f2bf(a.y) << 16);
    o.y = (uint)f2bf(a.z) | ((uint)f2bf(a.w) << 16);
    o.z = (uint)f2bf(b.x) | ((uint)f2bf(b.y) << 16);
    o.w = (uint)f2bf(b.z) | ((uint)f2bf(b.w) << 16);
    return o;
}

// ---------------------------------------------------------------------------
// BK=64 swizzled staging (4-wave blocks): LDS rows of 64 bf16 (128B).
// LDS[row][cc] = G[row][cc ^ (row&7)] via pre-swizzled SOURCE col; dest linear.
// Per-wave issues: ROWS/32 gload_lds.
// ---------------------------------------------------------------------------
template<int ROWS>
__device__ __forceinline__ void stage64(const ushort* __restrict__ g, int ldel,
                                        char* lds, int wid, int lane){
    const int rr = wid*8 + (lane >> 3);
    const int sc = ((lane & 7) ^ (lane >> 3)) * 8;   // swizzled src col (elems)
    #pragma unroll
    for (int r = 0; r < ROWS; r += 32)
        gl_lds16(g + (size_t)(r + rr)*ldel + sc, lds + (size_t)(r + wid*8)*128);
}

// fragment read: [row][64] bf16 rows with chunk XOR (row&7); c16 in 0..7
__device__ __forceinline__ bf16x8 frag(const char* lds, int row, int c16){
    return *(const bf16x8*)(lds + row*128 + (((c16) ^ (row & 7)) << 4));
}

// Counted-vmcnt pre-compute sync: after this, loads OLDER than the N newest
// have landed on all waves. N literal. sched_barrier stops post-RA hoisting.
#define SYNC_VMCNT(N)  do { \
    asm volatile("s_waitcnt vmcnt(" #N ")" ::: "memory"); \
    __builtin_amdgcn_s_barrier(); \
    __builtin_amdgcn_sched_barrier(0); } while(0)
// Post-compute: my LDS reads are complete (lgkmcnt 0) before signaling the
// buffer free for overwrite; memory clobber pins program order.
#define SYNC_FREE()    do { \
    asm volatile("s_waitcnt lgkmcnt(0)" ::: "memory"); \
    __builtin_amdgcn_s_barrier(); \
    __builtin_amdgcn_sched_barrier(0); } while(0)

// ---------------------------------------------------------------------------
// 1) Linear conversion/setup kernel: x->xb, W->w3b, cs table.
// ---------------------------------------------------------------------------
__global__ void k_conv(const void* __restrict__ x,  const void* __restrict__ wq,
                       const void* __restrict__ wk, const void* __restrict__ wv,
                       const void* __restrict__ R,
                       ushort* __restrict__ xb, ushort* __restrict__ w3b,
                       float2* __restrict__ cs){
    const int fl = detect_bf16((const ushort*)x);
    int idx = blockIdx.x*256 + threadIdx.x;
    if (idx < 262144){
        ((uint4*)xb)[idx] = ld8(x, (size_t)idx*8, fl);
    } else if (idx < 360448){
        int w = idx - 262144;
        const void* W = (w < 32768) ? wq : (w < 65536) ? wk : wv;
        ((uint4*)w3b)[w] = ld8(W, (size_t)(w & 32767)*8, fl);
    } else {
        int cidx = idx - 360448;
        int m = cidx >> 8, i = cidx & 255;
        float c, s;
        if (fl){
            const ushort* Rb = (const ushort*)R;
            size_t base = (size_t)m * DD * DD;
            c = bf2f(Rb[base + (size_t)(2*i)   * DD + 2*i]);
            s = bf2f(Rb[base + (size_t)(2*i+1) * DD + 2*i]);
        } else {
            float ex = -((float)i - 1.0f) * (1.0f/256.0f);
            float th = expf(ex * 9.210340371976184f);   // ln(10000)
            float ang = (float)m * th;
            c = cosf(ang); s = sinf(ang);
        }
        cs[cidx] = make_float2(c, s);
    }
}

// ---------------------------------------------------------------------------
// Shared compute step: 128x64-tile MFMA block (4M x 2N per wave layout).
// ---------------------------------------------------------------------------
__device__ __forceinline__ void step42(const char* lA, const char* lB,
                                       f32x4 (&acc)[4][2], int lane, int wr, int wc){
    #pragma unroll
    for (int kk = 0; kk < 2; ++kk){
        bf16x8 af[4], bv[2];
        #pragma unroll
        for (int i = 0; i < 4; i++)
            af[i] = frag(lA, wr + i*16 + (lane&15), kk*4 + (lane>>4));
        #pragma unroll
        for (int j = 0; j < 2; j++)
            bv[j] = frag(lB, wc + j*16 + (lane&15), kk*4 + (lane>>4));
        #pragma unroll
        for (int i = 0; i < 4; i++)
            #pragma unroll
            for (int j = 0; j < 2; j++)
                acc[i][j] = __builtin_amdgcn_mfma_f32_16x16x32_bf16(af[i], bv[j], acc[i][j], 0, 0, 0);
    }
}

// ---------------------------------------------------------------------------
// 2) QKV projection (y = x @ W^T) + RoPE (Q,K) / V^T emit. 128x64 tile,
//    BK=64 2-phase static dbuf + counted vmcnt(6), tail-corrected.
//    grid 768 (3/CU), XCD-clustered.
// ---------------------------------------------------------------------------
__launch_bounds__(256, 3)
__global__ void k_qkv(const ushort* __restrict__ xb, const ushort* __restrict__ w3b,
                      const float2* __restrict__ cs,
                      ushort* __restrict__ qr, ushort* __restrict__ kr,
                      ushort* __restrict__ vt){
    const int lin = blockIdx.x;                       // 768 blocks
    const int swz = (lin & 7) * 96 + (lin >> 3);      // XCD cluster of 96
    const int tm  = swz / 24;                         // 0..31
    const int rm  = swz % 24;
    const int mat = rm >> 3;                          // 0..2
    const int tn  = rm & 7;                           // 0..7 (fastest: share A)

    const ushort* A  = xb  + (size_t)(tm*128)*DD;
    const ushort* Bw = w3b + (size_t)mat*DD*DD + (size_t)(tn*64)*DD;

    const int t = threadIdx.x, lane = t & 63, wid = t >> 6;
    const int wr = (wid >> 1)*64, wc = (wid & 1)*32;

    __shared__ char A0[16384], A1[16384], B0[8192], B1[8192];   // 48KB

    f32x4 acc[4][2] = {};

    stage64<128>(A,  DD, A0, wid, lane);
    stage64<64> (Bw, DD, B0, wid, lane);
    #pragma unroll 1
    for (int kt = 0; kt < 6; kt += 2){
        stage64<128>(A  + (kt+1)*64, DD, A1, wid, lane);
        stage64<64> (Bw + (kt+1)*64, DD, B1, wid, lane);
        SYNC_VMCNT(6);                        // tile kt landed everywhere
        step42(A0, B0, acc, lane, wr, wc);
        SYNC_FREE();                          // A0/B0 free to overwrite
        stage64<128>(A  + (kt+2)*64, DD, A0, wid, lane);
        stage64<64> (Bw + (kt+2)*64, DD, B0, wid, lane);
        SYNC_VMCNT(6);                        // tile kt+1 landed
        step42(A1, B1, acc, lane, wr, wc);
        SYNC_FREE();
    }
    // tail: A0/B0 = tile 6 (in flight), stage tile 7, then full drain for it
    stage64<128>(A  + 7*64, DD, A1, wid, lane);
    stage64<64> (Bw + 7*64, DD, B1, wid, lane);
    SYNC_VMCNT(6);
    step42(A0, B0, acc, lane, wr, wc);
    SYNC_FREE();
    SYNC_VMCNT(0);                            // tile 7 fully landed
    step42(A1, B1, acc, lane, wr, wc);

    #pragma unroll
    for (int i = 0; i < 4; i++){
        #pragma unroll
        for (int j = 0; j < 2; j++){
            #pragma unroll
            for (int r = 0; r < 4; r++){
                int row = tm*128 + wr + i*16 + (lane>>4)*4 + r;   // global q row
                int col = tn*64 + wc + j*16 + (lane&15);          // output dim
                float v = acc[i][j][r];
                if (mat == 2){
                    vt[((size_t)(row >> 10)*DD + col)*MM + (row & (MM-1))] = f2bf(v);
                } else {
                    float p = __shfl_xor(v, 1);                   // partner col^1
                    float2 csv = cs[(row & (MM-1))*256 + (col >> 1)];
                    float o = (col & 1) ? (v*csv.x - p*csv.y) : (v*csv.x + p*csv.y);
                    ushort* out = (mat == 0) ? qr : kr;
                    out[(size_t)row*DD + col] = f2bf(o);
                }
            }
        }
    }
}

// ---------------------------------------------------------------------------
// 3) Pexp = exp(Qr @ Kr^T * scale - 8) as bf16. 128x64 tile, BK=64,
//    2-phase static dbuf + counted vmcnt(6), tail-corrected. grid 512 (2/CU).
// ---------------------------------------------------------------------------
__launch_bounds__(256, 2)
__global__ void k_sexp(const ushort* __restrict__ qr, const ushort* __restrict__ kr,
                       ushort* __restrict__ Pexp){
    const int lin = blockIdx.x;                       // 512 blocks
    const int swz = (lin & 7) * 64 + (lin >> 3);
    const int b   = swz >> 7;
    const int r7  = swz & 127;
    const int tm  = r7 >> 4;                          // 0..7
    const int tn  = r7 & 15;                          // 0..15 (fastest: share A)

    const ushort* A  = qr + (size_t)b*MM*DD + (size_t)(tm*128)*DD;
    const ushort* Bm = kr + (size_t)b*MM*DD + (size_t)(tn*64)*DD;
    ushort*      out = Pexp + (size_t)b*MM*MM;
    const float scale = 0.04419417382415922f;       // 1/sqrt(512)

    const int t = threadIdx.x, lane = t & 63, wid = t >> 6;
    const int wr = (wid >> 1)*64, wc = (wid & 1)*32;

    __shared__ char A0[16384], A1[16384], B0[8192], B1[8192];   // 48KB

    f32x4 acc[4][2] = {};

    stage64<128>(A,  DD, A0, wid, lane);
    stage64<64> (Bm, DD, B0, wid, lane);
    #pragma unroll 1
    for (int kt = 0; kt < 6; kt += 2){
        stage64<128>(A  + (kt+1)*64, DD, A1, wid, lane);
        stage64<64> (Bm + (kt+1)*64, DD, B1, wid, lane);
        SYNC_VMCNT(6);
        step42(A0, B0, acc, lane, wr, wc);
        SYNC_FREE();
        stage64<128>(A  + (kt+2)*64, DD, A0, wid, lane);
        stage64<64> (Bm + (kt+2)*64, DD, B0, wid, lane);
        SYNC_VMCNT(6);
        step42(A1, B1, acc, lane, wr, wc);
        SYNC_FREE();
    }
    stage64<128>(A  + 7*64, DD, A1, wid, lane);
    stage64<64> (Bm + 7*64, DD, B1, wid, lane);
    SYNC_VMCNT(6);
    step42(A0, B0, acc, lane, wr, wc);
    SYNC_FREE();
    SYNC_VMCNT(0);
    step42(A1, B1, acc, lane, wr, wc);

    #pragma unroll
    for (int i = 0; i < 4; i++)
        #pragma unroll
        for (int j = 0; j < 2; j++)
            #pragma unroll
            for (int r = 0; r < 4; r++){
                int row = tm*128 + wr + i*16 + (lane>>4)*4 + r;
                int col = tn*64 + wc + j*16 + (lane&15);
                float e = __expf(acc[i][j][r] * scale - 8.0f);
                out[(size_t)row*MM + col] = f2bf(e);
            }
}

// ---------------------------------------------------------------------------
// k_pv compute step (includes P row-sum accumulation).
// ---------------------------------------------------------------------------
__device__ __forceinline__ void pv_step(const char* lA, const char* lB,
                                        f32x4 (&acc)[2][2], float (&lsum)[2],
                                        int lane, int wr, int wc){
    #pragma unroll
    for (int kk = 0; kk < 2; ++kk){
        bf16x8 af[2], bv[2];
        #pragma unroll
        for (int i = 0; i < 2; i++){
            af[i] = frag(lA, wr + i*16 + (lane&15), kk*4 + (lane>>4));
            #pragma unroll
            for (int e = 0; e < 8; e++) lsum[i] += (float)af[i][e];
        }
        #pragma unroll
        for (int j = 0; j < 2; j++)
            bv[j] = frag(lB, wc + j*16 + (lane&15), kk*4 + (lane>>4));
        #pragma unroll
        for (int i = 0; i < 2; i++)
            #pragma unroll
            for (int j = 0; j < 2; j++)
                acc[i][j] = __builtin_amdgcn_mfma_f32_16x16x32_bf16(af[i], bv[j], acc[i][j], 0, 0, 0);
    }
}

// ---------------------------------------------------------------------------
// 4) O = (P @ V^T-rows) / rowsum(P). 64x64 tile, BK=64, 2-phase static dbuf
//    + counted vmcnt(4), tail-corrected. Row-sums from the SAME staged
//    A-fragments. grid 512 (2/CU).
// ---------------------------------------------------------------------------
__launch_bounds__(256, 2)
__global__ void k_pv(const ushort* __restrict__ P, const ushort* __restrict__ vt,
                     const ushort* __restrict__ xdet, void* __restrict__ O){
    const int lin = blockIdx.x;                       // 512 blocks
    const int swz = (lin & 7) * 64 + (lin >> 3);
    const int b   = swz >> 7;
    const int r7  = swz & 127;
    const int tm  = r7 >> 3;                          // 0..15
    const int tn  = r7 & 7;                           // 0..7 (fastest: share A)

    const int fl = detect_bf16(xdet);
    const ushort* A  = P  + ((size_t)b*MM + tm*64) * MM;   // bf16 rows, stride 1024
    const ushort* Bv = vt + (size_t)b*DD*MM + (size_t)(tn*64)*MM;

    const int t = threadIdx.x, lane = t & 63, wid = t >> 6;
    const int wr = (wid >> 1)*32, wc = (wid & 1)*32;

    __shared__ char A0[8192], A1[8192], B0[8192], B1[8192];   // 32KB

    f32x4 acc[2][2] = {};
    float lsum[2] = {0.0f, 0.0f};   // partial row-sum of P

    stage64<64>(A,  MM, A0, wid, lane);
    stage64<64>(Bv, MM, B0, wid, lane);
    #pragma unroll 1
    for (int kt = 0; kt < 14; kt += 2){
        stage64<64>(A  + (kt+1)*64, MM, A1, wid, lane);
        stage64<64>(Bv + (kt+1)*64, MM, B1, wid, lane);
        SYNC_VMCNT(4);
        pv_step(A0, B0, acc, lsum, lane, wr, wc);
        SYNC_FREE();
        stage64<64>(A  + (kt+2)*64, MM, A0, wid, lane);
        stage64<64>(Bv + (kt+2)*64, MM, B0, wid, lane);
        SYNC_VMCNT(4);
        pv_step(A1, B1, acc, lsum, lane, wr, wc);
        SYNC_FREE();
    }
    stage64<64>(A  + 15*64, MM, A1, wid, lane);
    stage64<64>(Bv + 15*64, MM, B1, wid, lane);
    SYNC_VMCNT(4);
    pv_step(A0, B0, acc, lsum, lane, wr, wc);
    SYNC_FREE();
    SYNC_VMCNT(0);
    pv_step(A1, B1, acc, lsum, lane, wr, wc);

    // complete row-sums: reduce over the 4 k-chunk lane groups (lane>>4)
    #pragma unroll
    for (int i = 0; i < 2; i++){
        lsum[i] += __shfl_xor(lsum[i], 16);
        lsum[i] += __shfl_xor(lsum[i], 32);
    }
    // redistribute: acc row16 index is (lane>>4)*4 + r; lsum lives at lane&15 == row16
    float linv[2][4];
    #pragma unroll
    for (int i = 0; i < 2; i++)
        #pragma unroll
        for (int r = 0; r < 4; r++)
            linv[i][r] = 1.0f / __shfl(lsum[i], (lane>>4)*4 + r);

    #pragma unroll
    for (int i = 0; i < 2; i++)
        #pragma unroll
        for (int j = 0; j < 2; j++)
            #pragma unroll
            for (int r = 0; r < 4; r++){
                int row = b*MM + tm*64 + wr + i*16 + (lane>>4)*4 + r;
                int col = tn*64 + wc + j*16 + (lane&15);
                float o = acc[i][j][r] * linv[i][r];
                if (fl) ((ushort*)O)[(size_t)row*DD + col] = f2bf(o);
                else    ((float*) O)[(size_t)row*DD + col] = o;
            }
}

// ---------------------------------------------------------------------------
extern "C" void kernel_launch(void* const* d_in, const int* in_sizes, int n_in,
                              void* d_out, int out_size, void* d_ws, size_t ws_size,
                              hipStream_t stream){
    const void* x  = d_in[0];
    const void* wq = d_in[1];
    const void* wk = d_in[2];
    const void* wv = d_in[3];
    const void* R  = d_in[4];

    char* ws = (char*)d_ws;
    // cs@0 (2MB), xb@2 (4MB), w3b@6 (1.5MB), qr@8 (4MB), kr@12 (4MB),
    // vt@16 (4MB), Pexp@20 (8MB) -> 28MB
    float2* cs  = (float2*)ws;
    ushort* xb  = (ushort*)(ws + (2u  << 20));
    ushort* w3b = (ushort*)(ws + (6u  << 20));
    ushort* qr  = (ushort*)(ws + (8u  << 20));
    ushort* kr  = (ushort*)(ws + (12u << 20));
    ushort* vt  = (ushort*)(ws + (16u << 20));
    ushort* Px  = (ushort*)(ws + (20u << 20));

    if (ws_size < (28u << 20)) return;

    k_conv<<<dim3(2432), dim3(256), 0, stream>>>(x, wq, wk, wv, R, xb, w3b, cs);
    k_qkv <<<dim3(768),  dim3(256), 0, stream>>>(xb, w3b, cs, qr, kr, vt);
    k_sexp<<<dim3(512),  dim3(256), 0, stream>>>(qr, kr, Px);
    k_pv  <<<dim3(512),  dim3(256), 0, stream>>>(Px, vt, (const ushort*)x, d_out);
}

// Round 14
// 52.894 us; speedup vs baseline: 1.0223x; 1.0223x over previous
//
#include <hip/hip_runtime.h>
#include <hip/hip_bf16.h>

// Shapes (fixed): B=4, M=1024, D=512. Device inputs f32 or bf16 (self-detected).
#define BB 4
#define MM 1024
#define DD 512
#define MT (BB*MM)          // 4096 total rows

typedef __bf16  bf16x8 __attribute__((ext_vector_type(8)));
typedef float   f32x4  __attribute__((ext_vector_type(4)));

typedef __attribute__((address_space(1))) const unsigned char gas_char;
typedef __attribute__((address_space(3))) unsigned char las_char;

__device__ __forceinline__ void gl_lds16(const void* g, void* l){
    // async global->LDS, 16B/lane; LDS dest = wave-uniform base + lane*16
    __builtin_amdgcn_global_load_lds((gas_char*)g, (las_char*)l, 16, 0, 0);
}

__device__ __forceinline__ float bf2f(ushort u){
    union{float f; unsigned u;} x; x.u = (unsigned)u << 16; return x.f;
}
__device__ __forceinline__ ushort f2bf(float f){
    union{float f; unsigned u;} x; x.f = f;
    unsigned r = x.u + 0x7FFF + ((x.u >> 16) & 1);   // RNE
    return (ushort)(r >> 16);
}

// Wave-uniform dtype detect: bf16 N(0,1) even half-words have sane exponents.
__device__ __forceinline__ int detect_bf16(const ushort* __restrict__ x){
    int lane = threadIdx.x & 63;
    ushort u = x[2*lane];
    int e = (u >> 7) & 0xFF;
    bool sane = (e >= 114 && e <= 140);
    unsigned long long b = __ballot(sane);
    return (__popcll(b) >= 48) ? 1 : 0;
}

// 8 consecutive elements at eidx (mult of 8) as packed bf16, converting if f32.
__device__ __forceinline__ uint4 ld8(const void* __restrict__ base, size_t eidx, int fl){
    if (fl) return ((const uint4*)base)[eidx >> 3];
    const float4* f = (const float4*)base + (eidx >> 2);
    float4 a = f[0], b = f[1];
    uint4 o;
    o.x = (uint)f2bf(a.x) | ((uint)f2bf(a.y) << 16);
    o.y = (uint)f2bf(a.z) | ((uint)f2bf(a.w) << 16);
    o.z = (uint)f2bf(b.x) | ((uint)f2bf(b.y) << 16);
    o.w = (uint)f2bf(b.z) | ((uint)f2bf(b.w) << 16);
    return o;
}

// ---------------------------------------------------------------------------
// BK=64 swizzled staging (4-wave blocks): LDS rows of 64 bf16 (128B).
// LDS[row][cc] = G[row][cc ^ (row&7)] via pre-swizzled SOURCE col; dest linear.
// Per-wave issues: ROWS/32 gload_lds.
// ---------------------------------------------------------------------------
template<int ROWS>
__device__ __forceinline__ void stage64(const ushort* __restrict__ g, int ldel,
                                        char* lds, int wid, int lane){
    const int rr = wid*8 + (lane >> 3);
    const int sc = ((lane & 7) ^ (lane >> 3)) * 8;   // swizzled src col (elems)
    #pragma unroll
    for (int r = 0; r < ROWS; r += 32)
        gl_lds16(g + (size_t)(r + rr)*ldel + sc, lds + (size_t)(r + wid*8)*128);
}

// fragment read: [row][64] bf16 rows with chunk XOR (row&7); c16 in 0..7
__device__ __forceinline__ bf16x8 frag(const char* lds, int row, int c16){
    return *(const bf16x8*)(lds + row*128 + (((c16) ^ (row & 7)) << 4));
}

// ---------------------------------------------------------------------------
// BK=128 swizzled staging (4-wave blocks): LDS rows of 128 bf16 (256B).
// ---------------------------------------------------------------------------
template<int ROWS>
__device__ __forceinline__ void stage128(const ushort* __restrict__ g, int ldel,
                                         char* lds, int wid, int lane){
    const int rr = wid*4 + (lane >> 4);              // row within 16-row group
    const int sc = (((lane & 15) ^ (rr & 7))) * 8;   // swizzled src col (elems)
    #pragma unroll
    for (int r = 0; r < ROWS; r += 16)
        gl_lds16(g + (size_t)(r + rr)*ldel + sc, lds + (size_t)(r + wid*4)*256);
}

// fragment read: [row][128] bf16 rows with chunk XOR (row&7); c16 in 0..15
__device__ __forceinline__ bf16x8 frag128(const char* lds, int row, int c16){
    return *(const bf16x8*)(lds + row*256 + (((c16) ^ (row & 7)) << 4));
}

// Counted-vmcnt pre-compute sync (NO sched_barrier — m141: order-pinning
// defeats compiler scheduling; compiler-emitted ds_reads carry their own
// lgkmcnt deps, so rule-18's hazard doesn't apply here).
#define SYNC_VMCNT(N)  do { \
    asm volatile("s_waitcnt vmcnt(" #N ")" ::: "memory"); \
    __builtin_amdgcn_s_barrier(); } while(0)
// Post-compute: LDS reads complete before buffer handed back for overwrite.
#define SYNC_FREE()    do { \
    asm volatile("s_waitcnt lgkmcnt(0)" ::: "memory"); \
    __builtin_amdgcn_s_barrier(); } while(0)

// ---------------------------------------------------------------------------
// 1) Linear conversion/setup kernel: x->xb, W->w3b, cs table.
// ---------------------------------------------------------------------------
__global__ void k_conv(const void* __restrict__ x,  const void* __restrict__ wq,
                       const void* __restrict__ wk, const void* __restrict__ wv,
                       const void* __restrict__ R,
                       ushort* __restrict__ xb, ushort* __restrict__ w3b,
                       float2* __restrict__ cs){
    const int fl = detect_bf16((const ushort*)x);
    int idx = blockIdx.x*256 + threadIdx.x;
    if (idx < 262144){
        ((uint4*)xb)[idx] = ld8(x, (size_t)idx*8, fl);
    } else if (idx < 360448){
        int w = idx - 262144;
        const void* W = (w < 32768) ? wq : (w < 65536) ? wk : wv;
        ((uint4*)w3b)[w] = ld8(W, (size_t)(w & 32767)*8, fl);
    } else {
        int cidx = idx - 360448;
        int m = cidx >> 8, i = cidx & 255;
        float c, s;
        if (fl){
            const ushort* Rb = (const ushort*)R;
            size_t base = (size_t)m * DD * DD;
            c = bf2f(Rb[base + (size_t)(2*i)   * DD + 2*i]);
            s = bf2f(Rb[base + (size_t)(2*i+1) * DD + 2*i]);
        } else {
            float ex = -((float)i - 1.0f) * (1.0f/256.0f);
            float th = expf(ex * 9.210340371976184f);   // ln(10000)
            float ang = (float)m * th;
            c = cosf(ang); s = sinf(ang);
        }
        cs[cidx] = make_float2(c, s);
    }
}

// ---------------------------------------------------------------------------
// 2) QKV projection (y = x @ W^T) + RoPE (Q,K) / V^T emit. 128x64 tile,
//    BK=128 single-buffer (r10/r11-proven best qkv config). grid 768 (3/CU).
// ---------------------------------------------------------------------------
__launch_bounds__(256, 3)
__global__ void k_qkv(const ushort* __restrict__ xb, const ushort* __restrict__ w3b,
                      const float2* __restrict__ cs,
                      ushort* __restrict__ qr, ushort* __restrict__ kr,
                      ushort* __restrict__ vt){
    const int lin = blockIdx.x;                       // 768 blocks
    const int swz = (lin & 7) * 96 + (lin >> 3);      // XCD cluster of 96
    const int tm  = swz / 24;                         // 0..31
    const int rm  = swz % 24;
    const int mat = rm >> 3;                          // 0..2
    const int tn  = rm & 7;                           // 0..7 (fastest: share A)

    const ushort* A  = xb  + (size_t)(tm*128)*DD;
    const ushort* Bw = w3b + (size_t)mat*DD*DD + (size_t)(tn*64)*DD;

    const int t = threadIdx.x, lane = t & 63, wid = t >> 6;
    const int wr = (wid >> 1)*64, wc = (wid & 1)*32;

    __shared__ char smem[49152];    // A[128][128] @0 (32KB), B[64][128] @32K (16KB)

    f32x4 acc[4][2] = {};

    #pragma unroll 1
    for (int kt = 0; kt < DD/128; ++kt){
        stage128<128>(A  + kt*128, DD, smem,       wid, lane);
        stage128<64> (Bw + kt*128, DD, smem+32768, wid, lane);
        __syncthreads();                          // drains vmcnt: tiles ready
        #pragma unroll
        for (int kk = 0; kk < 4; ++kk){
            bf16x8 af[4], bv[2];
            #pragma unroll
            for (int i = 0; i < 4; i++)
                af[i] = frag128(smem,       wr + i*16 + (lane&15), kk*4 + (lane>>4));
            #pragma unroll
            for (int j = 0; j < 2; j++)
                bv[j] = frag128(smem+32768, wc + j*16 + (lane&15), kk*4 + (lane>>4));
            #pragma unroll
            for (int i = 0; i < 4; i++)
                #pragma unroll
                for (int j = 0; j < 2; j++)
                    acc[i][j] = __builtin_amdgcn_mfma_f32_16x16x32_bf16(af[i], bv[j], acc[i][j], 0, 0, 0);
        }
        __syncthreads();                          // reads done before re-stage
    }

    #pragma unroll
    for (int i = 0; i < 4; i++){
        #pragma unroll
        for (int j = 0; j < 2; j++){
            #pragma unroll
            for (int r = 0; r < 4; r++){
                int row = tm*128 + wr + i*16 + (lane>>4)*4 + r;   // global q row
                int col = tn*64 + wc + j*16 + (lane&15);          // output dim
                float v = acc[i][j][r];
                if (mat == 2){
                    vt[((size_t)(row >> 10)*DD + col)*MM + (row & (MM-1))] = f2bf(v);
                } else {
                    float p = __shfl_xor(v, 1);                   // partner col^1
                    float2 csv = cs[(row & (MM-1))*256 + (col >> 1)];
                    float o = (col & 1) ? (v*csv.x - p*csv.y) : (v*csv.x + p*csv.y);
                    ushort* out = (mat == 0) ? qr : kr;
                    out[(size_t)row*DD + col] = f2bf(o);
                }
            }
        }
    }
}

// ---------------------------------------------------------------------------
// Shared compute step: 128x64-tile MFMA block (4M x 2N per wave layout).
// ---------------------------------------------------------------------------
__device__ __forceinline__ void step42(const char* lA, const char* lB,
                                       f32x4 (&acc)[4][2], int lane, int wr, int wc){
    #pragma unroll
    for (int kk = 0; kk < 2; ++kk){
        bf16x8 af[4], bv[2];
        #pragma unroll
        for (int i = 0; i < 4; i++)
            af[i] = frag(lA, wr + i*16 + (lane&15), kk*4 + (lane>>4));
        #pragma unroll
        for (int j = 0; j < 2; j++)
            bv[j] = frag(lB, wc + j*16 + (lane&15), kk*4 + (lane>>4));
        #pragma unroll
        for (int i = 0; i < 4; i++)
            #pragma unroll
            for (int j = 0; j < 2; j++)
                acc[i][j] = __builtin_amdgcn_mfma_f32_16x16x32_bf16(af[i], bv[j], acc[i][j], 0, 0, 0);
    }
}

// ---------------------------------------------------------------------------
// 3) Pexp = exp(Qr @ Kr^T * scale - 8) as bf16. 128x64 tile, BK=64,
//    2-phase static dbuf + counted vmcnt(6), tail-corrected (r13-verified),
//    NO sched_barrier. grid 512 (2/CU).
// ---------------------------------------------------------------------------
__launch_bounds__(256, 2)
__global__ void k_sexp(const ushort* __restrict__ qr, const ushort* __restrict__ kr,
                       ushort* __restrict__ Pexp){
    const int lin = blockIdx.x;                       // 512 blocks
    const int swz = (lin & 7) * 64 + (lin >> 3);
    const int b   = swz >> 7;
    const int r7  = swz & 127;
    const int tm  = r7 >> 4;                          // 0..7
    const int tn  = r7 & 15;                          // 0..15 (fastest: share A)

    const ushort* A  = qr + (size_t)b*MM*DD + (size_t)(tm*128)*DD;
    const ushort* Bm = kr + (size_t)b*MM*DD + (size_t)(tn*64)*DD;
    ushort*      out = Pexp + (size_t)b*MM*MM;
    const float scale = 0.04419417382415922f;       // 1/sqrt(512)

    const int t = threadIdx.x, lane = t & 63, wid = t >> 6;
    const int wr = (wid >> 1)*64, wc = (wid & 1)*32;

    __shared__ char A0[16384], A1[16384], B0[8192], B1[8192];   // 48KB

    f32x4 acc[4][2] = {};

    stage64<128>(A,  DD, A0, wid, lane);
    stage64<64> (Bm, DD, B0, wid, lane);
    #pragma unroll 1
    for (int kt = 0; kt < 6; kt += 2){
        stage64<128>(A  + (kt+1)*64, DD, A1, wid, lane);
        stage64<64> (Bm + (kt+1)*64, DD, B1, wid, lane);
        SYNC_VMCNT(6);                        // tile kt landed everywhere
        step42(A0, B0, acc, lane, wr, wc);
        SYNC_FREE();                          // A0/B0 free to overwrite
        stage64<128>(A  + (kt+2)*64, DD, A0, wid, lane);
        stage64<64> (Bm + (kt+2)*64, DD, B0, wid, lane);
        SYNC_VMCNT(6);                        // tile kt+1 landed
        step42(A1, B1, acc, lane, wr, wc);
        SYNC_FREE();
    }
    // tail: tile 6 in flight in A0/B0; stage tile 7; drain correctly
    stage64<128>(A  + 7*64, DD, A1, wid, lane);
    stage64<64> (Bm + 7*64, DD, B1, wid, lane);
    SYNC_VMCNT(6);                            // tile 6 landed
    step42(A0, B0, acc, lane, wr, wc);
    SYNC_FREE();
    SYNC_VMCNT(0);                            // tile 7 fully landed
    step42(A1, B1, acc, lane, wr, wc);

    #pragma unroll
    for (int i = 0; i < 4; i++)
        #pragma unroll
        for (int j = 0; j < 2; j++)
            #pragma unroll
            for (int r = 0; r < 4; r++){
                int row = tm*128 + wr + i*16 + (lane>>4)*4 + r;
                int col = tn*64 + wc + j*16 + (lane&15);
                float e = __expf(acc[i][j][r] * scale - 8.0f);
                out[(size_t)row*MM + col] = f2bf(e);
            }
}

// ---------------------------------------------------------------------------
// k_pv compute step (includes P row-sum accumulation).
// ---------------------------------------------------------------------------
__device__ __forceinline__ void pv_step(const char* lA, const char* lB,
                                        f32x4 (&acc)[2][2], float (&lsum)[2],
                                        int lane, int wr, int wc){
    #pragma unroll
    for (int kk = 0; kk < 2; ++kk){
        bf16x8 af[2], bv[2];
        #pragma unroll
        for (int i = 0; i < 2; i++){
            af[i] = frag(lA, wr + i*16 + (lane&15), kk*4 + (lane>>4));
            #pragma unroll
            for (int e = 0; e < 8; e++) lsum[i] += (float)af[i][e];
        }
        #pragma unroll
        for (int j = 0; j < 2; j++)
            bv[j] = frag(lB, wc + j*16 + (lane&15), kk*4 + (lane>>4));
        #pragma unroll
        for (int i = 0; i < 2; i++)
            #pragma unroll
            for (int j = 0; j < 2; j++)
                acc[i][j] = __builtin_amdgcn_mfma_f32_16x16x32_bf16(af[i], bv[j], acc[i][j], 0, 0, 0);
    }
}

// ---------------------------------------------------------------------------
// 4) O = (P @ V^T-rows) / rowsum(P). 64x64 tile, BK=64, 2-phase static dbuf
//    + counted vmcnt(4), tail-corrected, NO sched_barrier. grid 512 (2/CU).
// ---------------------------------------------------------------------------
__launch_bounds__(256, 2)
__global__ void k_pv(const ushort* __restrict__ P, const ushort* __restrict__ vt,
                     const ushort* __restrict__ xdet, void* __restrict__ O){
    const int lin = blockIdx.x;                       // 512 blocks
    const int swz = (lin & 7) * 64 + (lin >> 3);
    const int b   = swz >> 7;
    const int r7  = swz & 127;
    const int tm  = r7 >> 3;                          // 0..15
    const int tn  = r7 & 7;                           // 0..7 (fastest: share A)

    const int fl = detect_bf16(xdet);
    const ushort* A  = P  + ((size_t)b*MM + tm*64) * MM;   // bf16 rows, stride 1024
    const ushort* Bv = vt + (size_t)b*DD*MM + (size_t)(tn*64)*MM;

    const int t = threadIdx.x, lane = t & 63, wid = t >> 6;
    const int wr = (wid >> 1)*32, wc = (wid & 1)*32;

    __shared__ char A0[8192], A1[8192], B0[8192], B1[8192];   // 32KB

    f32x4 acc[2][2] = {};
    float lsum[2] = {0.0f, 0.0f};   // partial row-sum of P

    stage64<64>(A,  MM, A0, wid, lane);
    stage64<64>(Bv, MM, B0, wid, lane);
    #pragma unroll 1
    for (int kt = 0; kt < 14; kt += 2){
        stage64<64>(A  + (kt+1)*64, MM, A1, wid, lane);
        stage64<64>(Bv + (kt+1)*64, MM, B1, wid, lane);
        SYNC_VMCNT(4);
        pv_step(A0, B0, acc, lsum, lane, wr, wc);
        SYNC_FREE();
        stage64<64>(A  + (kt+2)*64, MM, A0, wid, lane);
        stage64<64>(Bv + (kt+2)*64, MM, B0, wid, lane);
        SYNC_VMCNT(4);
        pv_step(A1, B1, acc, lsum, lane, wr, wc);
        SYNC_FREE();
    }
    stage64<64>(A  + 15*64, MM, A1, wid, lane);
    stage64<64>(Bv + 15*64, MM, B1, wid, lane);
    SYNC_VMCNT(4);
    pv_step(A0, B0, acc, lsum, lane, wr, wc);
    SYNC_FREE();
    SYNC_VMCNT(0);
    pv_step(A1, B1, acc, lsum, lane, wr, wc);

    // complete row-sums: reduce over the 4 k-chunk lane groups (lane>>4)
    #pragma unroll
    for (int i = 0; i < 2; i++){
        lsum[i] += __shfl_xor(lsum[i], 16);
        lsum[i] += __shfl_xor(lsum[i], 32);
    }
    // redistribute: acc row16 index is (lane>>4)*4 + r; lsum lives at lane&15 == row16
    float linv[2][4];
    #pragma unroll
    for (int i = 0; i < 2; i++)
        #pragma unroll
        for (int r = 0; r < 4; r++)
            linv[i][r] = 1.0f / __shfl(lsum[i], (lane>>4)*4 + r);

    #pragma unroll
    for (int i = 0; i < 2; i++)
        #pragma unroll
        for (int j = 0; j < 2; j++)
            #pragma unroll
            for (int r = 0; r < 4; r++){
                int row = b*MM + tm*64 + wr + i*16 + (lane>>4)*4 + r;
                int col = tn*64 + wc + j*16 + (lane&15);
                float o = acc[i][j][r] * linv[i][r];
                if (fl) ((ushort*)O)[(size_t)row*DD + col] = f2bf(o);
                else    ((float*) O)[(size_t)row*DD + col] = o;
            }
}

// ---------------------------------------------------------------------------
extern "C" void kernel_launch(void* const* d_in, const int* in_sizes, int n_in,
                              void* d_out, int out_size, void* d_ws, size_t ws_size,
                              hipStream_t stream){
    const void* x  = d_in[0];
    const void* wq = d_in[1];
    const void* wk = d_in[2];
    const void* wv = d_in[3];
    const void* R  = d_in[4];

    char* ws = (char*)d_ws;
    // cs@0 (2MB), xb@2 (4MB), w3b@6 (1.5MB), qr@8 (4MB), kr@12 (4MB),
    // vt@16 (4MB), Pexp@20 (8MB) -> 28MB
    float2* cs  = (float2*)ws;
    ushort* xb  = (ushort*)(ws + (2u  << 20));
    ushort* w3b = (ushort*)(ws + (6u  << 20));
    ushort* qr  = (ushort*)(ws + (8u  << 20));
    ushort* kr  = (ushort*)(ws + (12u << 20));
    ushort* vt  = (ushort*)(ws + (16u << 20));
    ushort* Px  = (ushort*)(ws + (20u << 20));

    if (ws_size < (28u << 20)) return;

    k_conv<<<dim3(2432), dim3(256), 0, stream>>>(x, wq, wk, wv, R, xb, w3b, cs);
    k_qkv <<<dim3(768),  dim3(256), 0, stream>>>(xb, w3b, cs, qr, kr, vt);
    k_sexp<<<dim3(512),  dim3(256), 0, stream>>>(qr, kr, Px);
    k_pv  <<<dim3(512),  dim3(256), 0, stream>>>(Px, vt, (const ushort*)x, d_out);
}

// Round 15
// 52.213 us; speedup vs baseline: 1.0356x; 1.0130x over previous
//
#include <hip/hip_runtime.h>
#include <hip/hip_bf16.h>

// Shapes (fixed): B=4, M=1024, D=512. Device inputs f32 or bf16 (self-detected).
#define BB 4
#define MM 1024
#define DD 512
#define MT (BB*MM)          // 4096 total rows

typedef __bf16  bf16x8 __attribute__((ext_vector_type(8)));
typedef float   f32x4  __attribute__((ext_vector_type(4)));

typedef __attribute__((address_space(1))) const unsigned char gas_char;
typedef __attribute__((address_space(3))) unsigned char las_char;

__device__ __forceinline__ void gl_lds16(const void* g, void* l){
    // async global->LDS, 16B/lane; LDS dest = wave-uniform base + lane*16
    __builtin_amdgcn_global_load_lds((gas_char*)g, (las_char*)l, 16, 0, 0);
}

__device__ __forceinline__ float bf2f(ushort u){
    union{float f; unsigned u;} x; x.u = (unsigned)u << 16; return x.f;
}
__device__ __forceinline__ ushort f2bf(float f){
    union{float f; unsigned u;} x; x.f = f;
    unsigned r = x.u + 0x7FFF + ((x.u >> 16) & 1);   // RNE
    return (ushort)(r >> 16);
}

// Wave-uniform dtype detect: bf16 N(0,1) even half-words have sane exponents.
__device__ __forceinline__ int detect_bf16(const ushort* __restrict__ x){
    int lane = threadIdx.x & 63;
    ushort u = x[2*lane];
    int e = (u >> 7) & 0xFF;
    bool sane = (e >= 114 && e <= 140);
    unsigned long long b = __ballot(sane);
    return (__popcll(b) >= 48) ? 1 : 0;
}

// 8 consecutive elements at eidx (mult of 8) as packed bf16, converting if f32.
__device__ __forceinline__ uint4 ld8(const void* __restrict__ base, size_t eidx, int fl){
    if (fl) return ((const uint4*)base)[eidx >> 3];
    const float4* f = (const float4*)base + (eidx >> 2);
    float4 a = f[0], b = f[1];
    uint4 o;
    o.x = (uint)f2bf(a.x) | ((uint)f2bf(a.y) << 16);
    o.y = (uint)f2bf(a.z) | ((uint)f2bf(a.w) << 16);
    o.z = (uint)f2bf(b.x) | ((uint)f2bf(b.y) << 16);
    o.w = (uint)f2bf(b.z) | ((uint)f2bf(b.w) << 16);
    return o;
}

// ---------------------------------------------------------------------------
// BK=64 swizzled staging (4-wave blocks): LDS rows of 64 bf16 (128B).
// LDS[row][cc] = G[row][cc ^ (row&7)] via pre-swizzled SOURCE col; dest linear.
// ---------------------------------------------------------------------------
template<int ROWS>
__device__ __forceinline__ void stage64(const ushort* __restrict__ g, int ldel,
                                        char* lds, int wid, int lane){
    const int rr = wid*8 + (lane >> 3);
    const int sc = ((lane & 7) ^ (lane >> 3)) * 8;   // swizzled src col (elems)
    #pragma unroll
    for (int r = 0; r < ROWS; r += 32)
        gl_lds16(g + (size_t)(r + rr)*ldel + sc, lds + (size_t)(r + wid*8)*128);
}

// fragment read: [row][64] bf16 rows with chunk XOR (row&7); c16 in 0..7
__device__ __forceinline__ bf16x8 frag(const char* lds, int row, int c16){
    return *(const bf16x8*)(lds + row*128 + (((c16) ^ (row & 7)) << 4));
}

// ---------------------------------------------------------------------------
// BK=128 swizzled staging (4-wave blocks): LDS rows of 128 bf16 (256B).
// Per-wave issues: ROWS/16.
// ---------------------------------------------------------------------------
template<int ROWS>
__device__ __forceinline__ void stage128(const ushort* __restrict__ g, int ldel,
                                         char* lds, int wid, int lane){
    const int rr = wid*4 + (lane >> 4);              // row within 16-row group
    const int sc = (((lane & 15) ^ (rr & 7))) * 8;   // swizzled src col (elems)
    #pragma unroll
    for (int r = 0; r < ROWS; r += 16)
        gl_lds16(g + (size_t)(r + rr)*ldel + sc, lds + (size_t)(r + wid*4)*256);
}

// fragment read: [row][128] bf16 rows with chunk XOR (row&7); c16 in 0..15
__device__ __forceinline__ bf16x8 frag128(const char* lds, int row, int c16){
    return *(const bf16x8*)(lds + row*256 + (((c16) ^ (row & 7)) << 4));
}

// Counted-vmcnt pre-compute sync (no sched_barrier — m141).
#define SYNC_VMCNT(N)  do { \
    asm volatile("s_waitcnt vmcnt(" #N ")" ::: "memory"); \
    __builtin_amdgcn_s_barrier(); } while(0)
// Post-compute: LDS reads complete before buffer handed back for overwrite.
#define SYNC_FREE()    do { \
    asm volatile("s_waitcnt lgkmcnt(0)" ::: "memory"); \
    __builtin_amdgcn_s_barrier(); } while(0)

// ---------------------------------------------------------------------------
// 1) Linear conversion/setup: x->xb, W->w3b, cs table. 4 chunks/thread (ILP),
//    grid 608 x 256 covering 622592 idx exactly.
// ---------------------------------------------------------------------------
__global__ void k_conv(const void* __restrict__ x,  const void* __restrict__ wq,
                       const void* __restrict__ wk, const void* __restrict__ wv,
                       const void* __restrict__ R,
                       ushort* __restrict__ xb, ushort* __restrict__ w3b,
                       float2* __restrict__ cs){
    const int fl = detect_bf16((const ushort*)x);
    const int base = blockIdx.x*1024 + threadIdx.x;
    #pragma unroll
    for (int q = 0; q < 4; ++q){
        int idx = base + q*256;
        if (idx < 262144){
            ((uint4*)xb)[idx] = ld8(x, (size_t)idx*8, fl);
        } else if (idx < 360448){
            int w = idx - 262144;
            const void* W = (w < 32768) ? wq : (w < 65536) ? wk : wv;
            ((uint4*)w3b)[w] = ld8(W, (size_t)(w & 32767)*8, fl);
        } else {
            int cidx = idx - 360448;
            int m = cidx >> 8, i = cidx & 255;
            float c, s;
            if (fl){
                const ushort* Rb = (const ushort*)R;
                size_t rb = (size_t)m * DD * DD;
                c = bf2f(Rb[rb + (size_t)(2*i)   * DD + 2*i]);
                s = bf2f(Rb[rb + (size_t)(2*i+1) * DD + 2*i]);
            } else {
                float ex = -((float)i - 1.0f) * (1.0f/256.0f);
                float th = expf(ex * 9.210340371976184f);   // ln(10000)
                float ang = (float)m * th;
                c = cosf(ang); s = sinf(ang);
            }
            cs[cidx] = make_float2(c, s);
        }
    }
}

// ---------------------------------------------------------------------------
// 2) QKV projection (y = x @ W^T) + RoPE (Q,K) / V^T emit. 128x64 tile,
//    BK=128 single-buffer (r10/r11-proven best qkv config). grid 768 (3/CU).
// ---------------------------------------------------------------------------
__launch_bounds__(256, 3)
__global__ void k_qkv(const ushort* __restrict__ xb, const ushort* __restrict__ w3b,
                      const float2* __restrict__ cs,
                      ushort* __restrict__ qr, ushort* __restrict__ kr,
                      ushort* __restrict__ vt){
    const int lin = blockIdx.x;                       // 768 blocks
    const int swz = (lin & 7) * 96 + (lin >> 3);      // XCD cluster of 96
    const int tm  = swz / 24;                         // 0..31
    const int rm  = swz % 24;
    const int mat = rm >> 3;                          // 0..2
    const int tn  = rm & 7;                           // 0..7 (fastest: share A)

    const ushort* A  = xb  + (size_t)(tm*128)*DD;
    const ushort* Bw = w3b + (size_t)mat*DD*DD + (size_t)(tn*64)*DD;

    const int t = threadIdx.x, lane = t & 63, wid = t >> 6;
    const int wr = (wid >> 1)*64, wc = (wid & 1)*32;

    __shared__ char smem[49152];    // A[128][128] @0 (32KB), B[64][128] @32K (16KB)

    f32x4 acc[4][2] = {};

    #pragma unroll 1
    for (int kt = 0; kt < DD/128; ++kt){
        stage128<128>(A  + kt*128, DD, smem,       wid, lane);
        stage128<64> (Bw + kt*128, DD, smem+32768, wid, lane);
        __syncthreads();                          // drains vmcnt: tiles ready
        #pragma unroll
        for (int kk = 0; kk < 4; ++kk){
            bf16x8 af[4], bv[2];
            #pragma unroll
            for (int i = 0; i < 4; i++)
                af[i] = frag128(smem,       wr + i*16 + (lane&15), kk*4 + (lane>>4));
            #pragma unroll
            for (int j = 0; j < 2; j++)
                bv[j] = frag128(smem+32768, wc + j*16 + (lane&15), kk*4 + (lane>>4));
            #pragma unroll
            for (int i = 0; i < 4; i++)
                #pragma unroll
                for (int j = 0; j < 2; j++)
                    acc[i][j] = __builtin_amdgcn_mfma_f32_16x16x32_bf16(af[i], bv[j], acc[i][j], 0, 0, 0);
        }
        __syncthreads();                          // reads done before re-stage
    }

    #pragma unroll
    for (int i = 0; i < 4; i++){
        #pragma unroll
        for (int j = 0; j < 2; j++){
            #pragma unroll
            for (int r = 0; r < 4; r++){
                int row = tm*128 + wr + i*16 + (lane>>4)*4 + r;   // global q row
                int col = tn*64 + wc + j*16 + (lane&15);          // output dim
                float v = acc[i][j][r];
                if (mat == 2){
                    vt[((size_t)(row >> 10)*DD + col)*MM + (row & (MM-1))] = f2bf(v);
                } else {
                    float p = __shfl_xor(v, 1);                   // partner col^1
                    float2 csv = cs[(row & (MM-1))*256 + (col >> 1)];
                    float o = (col & 1) ? (v*csv.x - p*csv.y) : (v*csv.x + p*csv.y);
                    ushort* out = (mat == 0) ? qr : kr;
                    out[(size_t)row*DD + col] = f2bf(o);
                }
            }
        }
    }
}

// ---------------------------------------------------------------------------
// Shared compute step: 128x64-tile MFMA block (4M x 2N per wave layout).
// ---------------------------------------------------------------------------
__device__ __forceinline__ void step42(const char* lA, const char* lB,
                                       f32x4 (&acc)[4][2], int lane, int wr, int wc){
    #pragma unroll
    for (int kk = 0; kk < 2; ++kk){
        bf16x8 af[4], bv[2];
        #pragma unroll
        for (int i = 0; i < 4; i++)
            af[i] = frag(lA, wr + i*16 + (lane&15), kk*4 + (lane>>4));
        #pragma unroll
        for (int j = 0; j < 2; j++)
            bv[j] = frag(lB, wc + j*16 + (lane&15), kk*4 + (lane>>4));
        #pragma unroll
        for (int i = 0; i < 4; i++)
            #pragma unroll
            for (int j = 0; j < 2; j++)
                acc[i][j] = __builtin_amdgcn_mfma_f32_16x16x32_bf16(af[i], bv[j], acc[i][j], 0, 0, 0);
    }
}

// ---------------------------------------------------------------------------
// 3) Pexp = exp(Qr @ Kr^T * scale - 8) as bf16. 128x64 tile, BK=64,
//    2-phase static dbuf + counted vmcnt(6), tail-corrected (r13/r14-proven).
//    grid 512 (2/CU).
// ---------------------------------------------------------------------------
__launch_bounds__(256, 2)
__global__ void k_sexp(const ushort* __restrict__ qr, const ushort* __restrict__ kr,
                       ushort* __restrict__ Pexp){
    const int lin = blockIdx.x;                       // 512 blocks
    const int swz = (lin & 7) * 64 + (lin >> 3);
    const int b   = swz >> 7;
    const int r7  = swz & 127;
    const int tm  = r7 >> 4;                          // 0..7
    const int tn  = r7 & 15;                          // 0..15 (fastest: share A)

    const ushort* A  = qr + (size_t)b*MM*DD + (size_t)(tm*128)*DD;
    const ushort* Bm = kr + (size_t)b*MM*DD + (size_t)(tn*64)*DD;
    ushort*      out = Pexp + (size_t)b*MM*MM;
    const float scale = 0.04419417382415922f;       // 1/sqrt(512)

    const int t = threadIdx.x, lane = t & 63, wid = t >> 6;
    const int wr = (wid >> 1)*64, wc = (wid & 1)*32;

    __shared__ char A0[16384], A1[16384], B0[8192], B1[8192];   // 48KB

    f32x4 acc[4][2] = {};

    stage64<128>(A,  DD, A0, wid, lane);
    stage64<64> (Bm, DD, B0, wid, lane);
    #pragma unroll 1
    for (int kt = 0; kt < 6; kt += 2){
        stage64<128>(A  + (kt+1)*64, DD, A1, wid, lane);
        stage64<64> (Bm + (kt+1)*64, DD, B1, wid, lane);
        SYNC_VMCNT(6);                        // tile kt landed everywhere
        step42(A0, B0, acc, lane, wr, wc);
        SYNC_FREE();                          // A0/B0 free to overwrite
        stage64<128>(A  + (kt+2)*64, DD, A0, wid, lane);
        stage64<64> (Bm + (kt+2)*64, DD, B0, wid, lane);
        SYNC_VMCNT(6);                        // tile kt+1 landed
        step42(A1, B1, acc, lane, wr, wc);
        SYNC_FREE();
    }
    // tail: tile 6 in flight in A0/B0; stage tile 7; drain correctly
    stage64<128>(A  + 7*64, DD, A1, wid, lane);
    stage64<64> (Bm + 7*64, DD, B1, wid, lane);
    SYNC_VMCNT(6);                            // tile 6 landed
    step42(A0, B0, acc, lane, wr, wc);
    SYNC_FREE();
    SYNC_VMCNT(0);                            // tile 7 fully landed
    step42(A1, B1, acc, lane, wr, wc);

    #pragma unroll
    for (int i = 0; i < 4; i++)
        #pragma unroll
        for (int j = 0; j < 2; j++)
            #pragma unroll
            for (int r = 0; r < 4; r++){
                int row = tm*128 + wr + i*16 + (lane>>4)*4 + r;
                int col = tn*64 + wc + j*16 + (lane&15);
                float e = __expf(acc[i][j][r] * scale - 8.0f);
                out[(size_t)row*MM + col] = f2bf(e);
            }
}

// ---------------------------------------------------------------------------
// k_pv BK=128 compute step (includes P row-sum accumulation).
// ---------------------------------------------------------------------------
__device__ __forceinline__ void pv_step128(const char* lA, const char* lB,
                                           f32x4 (&acc)[2][2], float (&lsum)[2],
                                           int lane, int wr, int wc){
    #pragma unroll
    for (int kk = 0; kk < 4; ++kk){
        bf16x8 af[2], bv[2];
        #pragma unroll
        for (int i = 0; i < 2; i++){
            af[i] = frag128(lA, wr + i*16 + (lane&15), kk*4 + (lane>>4));
            #pragma unroll
            for (int e = 0; e < 8; e++) lsum[i] += (float)af[i][e];
        }
        #pragma unroll
        for (int j = 0; j < 2; j++)
            bv[j] = frag128(lB, wc + j*16 + (lane&15), kk*4 + (lane>>4));
        #pragma unroll
        for (int i = 0; i < 2; i++)
            #pragma unroll
            for (int j = 0; j < 2; j++)
                acc[i][j] = __builtin_amdgcn_mfma_f32_16x16x32_bf16(af[i], bv[j], acc[i][j], 0, 0, 0);
    }
}

// ---------------------------------------------------------------------------
// 4) O = (P @ V^T-rows) / rowsum(P). 64x64 tile, BK=128 (8 K-steps),
//    2-phase static dbuf + counted vmcnt(8), tail-corrected. 64KB LDS, 2/CU.
//    grid 512.
// ---------------------------------------------------------------------------
__launch_bounds__(256, 2)
__global__ void k_pv(const ushort* __restrict__ P, const ushort* __restrict__ vt,
                     const ushort* __restrict__ xdet, void* __restrict__ O){
    const int lin = blockIdx.x;                       // 512 blocks
    const int swz = (lin & 7) * 64 + (lin >> 3);
    const int b   = swz >> 7;
    const int r7  = swz & 127;
    const int tm  = r7 >> 3;                          // 0..15
    const int tn  = r7 & 7;                           // 0..7 (fastest: share A)

    const int fl = detect_bf16(xdet);
    const ushort* A  = P  + ((size_t)b*MM + tm*64) * MM;   // bf16 rows, stride 1024
    const ushort* Bv = vt + (size_t)b*DD*MM + (size_t)(tn*64)*MM;

    const int t = threadIdx.x, lane = t & 63, wid = t >> 6;
    const int wr = (wid >> 1)*32, wc = (wid & 1)*32;

    __shared__ char A0[16384], A1[16384], B0[16384], B1[16384];   // 64KB

    f32x4 acc[2][2] = {};
    float lsum[2] = {0.0f, 0.0f};   // partial row-sum of P

    stage128<64>(A,  MM, A0, wid, lane);
    stage128<64>(Bv, MM, B0, wid, lane);
    #pragma unroll 1
    for (int kt = 0; kt < 6; kt += 2){
        stage128<64>(A  + (kt+1)*128, MM, A1, wid, lane);
        stage128<64>(Bv + (kt+1)*128, MM, B1, wid, lane);
        SYNC_VMCNT(8);                        // tile kt landed
        pv_step128(A0, B0, acc, lsum, lane, wr, wc);
        SYNC_FREE();
        stage128<64>(A  + (kt+2)*128, MM, A0, wid, lane);
        stage128<64>(Bv + (kt+2)*128, MM, B0, wid, lane);
        SYNC_VMCNT(8);                        // tile kt+1 landed
        pv_step128(A1, B1, acc, lsum, lane, wr, wc);
        SYNC_FREE();
    }
    // tail: tile 6 in flight in A0/B0; stage tile 7; drain correctly
    stage128<64>(A  + 7*128, MM, A1, wid, lane);
    stage128<64>(Bv + 7*128, MM, B1, wid, lane);
    SYNC_VMCNT(8);                            // tile 6 landed
    pv_step128(A0, B0, acc, lsum, lane, wr, wc);
    SYNC_FREE();
    SYNC_VMCNT(0);                            // tile 7 fully landed
    pv_step128(A1, B1, acc, lsum, lane, wr, wc);

    // complete row-sums: reduce over the 4 k-chunk lane groups (lane>>4)
    #pragma unroll
    for (int i = 0; i < 2; i++){
        lsum[i] += __shfl_xor(lsum[i], 16);
        lsum[i] += __shfl_xor(lsum[i], 32);
    }
    // redistribute: acc row16 index is (lane>>4)*4 + r; lsum lives at lane&15 == row16
    float linv[2][4];
    #pragma unroll
    for (int i = 0; i < 2; i++)
        #pragma unroll
        for (int r = 0; r < 4; r++)
            linv[i][r] = 1.0f / __shfl(lsum[i], (lane>>4)*4 + r);

    #pragma unroll
    for (int i = 0; i < 2; i++)
        #pragma unroll
        for (int j = 0; j < 2; j++)
            #pragma unroll
            for (int r = 0; r < 4; r++){
                int row = b*MM + tm*64 + wr + i*16 + (lane>>4)*4 + r;
                int col = tn*64 + wc + j*16 + (lane&15);
                float o = acc[i][j][r] * linv[i][r];
                if (fl) ((ushort*)O)[(size_t)row*DD + col] = f2bf(o);
                else    ((float*) O)[(size_t)row*DD + col] = o;
            }
}

// ---------------------------------------------------------------------------
extern "C" void kernel_launch(void* const* d_in, const int* in_sizes, int n_in,
                              void* d_out, int out_size, void* d_ws, size_t ws_size,
                              hipStream_t stream){
    const void* x  = d_in[0];
    const void* wq = d_in[1];
    const void* wk = d_in[2];
    const void* wv = d_in[3];
    const void* R  = d_in[4];

    char* ws = (char*)d_ws;
    // cs@0 (2MB), xb@2 (4MB), w3b@6 (1.5MB), qr@8 (4MB), kr@12 (4MB),
    // vt@16 (4MB), Pexp@20 (8MB) -> 28MB
    float2* cs  = (float2*)ws;
    ushort* xb  = (ushort*)(ws + (2u  << 20));
    ushort* w3b = (ushort*)(ws + (6u  << 20));
    ushort* qr  = (ushort*)(ws + (8u  << 20));
    ushort* kr  = (ushort*)(ws + (12u << 20));
    ushort* vt  = (ushort*)(ws + (16u << 20));
    ushort* Px  = (ushort*)(ws + (20u << 20));

    if (ws_size < (28u << 20)) return;

    k_conv<<<dim3(608),  dim3(256), 0, stream>>>(x, wq, wk, wv, R, xb, w3b, cs);
    k_qkv <<<dim3(768),  dim3(256), 0, stream>>>(xb, w3b, cs, qr, kr, vt);
    k_sexp<<<dim3(512),  dim3(256), 0, stream>>>(qr, kr, Px);
    k_pv  <<<dim3(512),  dim3(256), 0, stream>>>(Px, vt, (const ushort*)x, d_out);
}